// Round 4
// baseline (1202.189 us; speedup 1.0000x reference)
//
#include <hip/hip_runtime.h>
#include <stdint.h>

#define N_ROWS 32768
#define N_E    4096
#define E_DIM  256

// sortable-uint encoding for float max-compare
__device__ __forceinline__ unsigned int f2sort(float s) {
    unsigned int b = __float_as_uint(s);
    return (b & 0x80000000u) ? ~b : (b | 0x80000000u);
}

// ---------- kernel 1: f32 row norms (f64 accumulate, cast to f32) ----------
__global__ __launch_bounds__(256) void k_rownorm(const float* __restrict__ src,
                                                 float* __restrict__ outf) {
    int j = blockIdx.x * 4 + (threadIdx.x >> 6);
    int lane = threadIdx.x & 63;
    const float4* e4 = (const float4*)(src + (size_t)j * E_DIM);
    float4 v = e4[lane];
    double s = (double)v.x * v.x + (double)v.y * v.y + (double)v.z * v.z + (double)v.w * v.w;
    #pragma unroll
    for (int off = 1; off < 64; off <<= 1) s += __shfl_xor(s, off);
    if (lane == 0) outf[j] = (float)s;
}

// ---------- kernel 2: f32 GEMM + collapsed-f32 argmin (replicates np ref) ----------
// q_rj = fl32( fl32(Cz_r + Ce_j) - 2*dot32_rj ); argmin_j with lowest-index ties.
__global__ __launch_bounds__(256, 1) void k_passA(const float* __restrict__ z,
                                                  const float* __restrict__ emb,
                                                  const float* __restrict__ enf,
                                                  const float* __restrict__ znf,
                                                  int* __restrict__ idx) {
    __shared__ float As[32][128];
    __shared__ float Bs[32][128];
    const int tid  = threadIdx.x;
    const int tcol = tid & 15;
    const int trow = tid >> 4;
    const int row0 = blockIdx.x * 128;

    unsigned long long key[8];
    float czr[8];
    #pragma unroll
    for (int i = 0; i < 8; i++) {
        key[i] = 0ull;
        czr[i] = znf[row0 + trow * 4 + (i & 3) + (i >> 2) * 64];
    }

    for (int jt = 0; jt < 32; ++jt) {
        float acc[8][8];
        #pragma unroll
        for (int i = 0; i < 8; i++)
            #pragma unroll
            for (int jj = 0; jj < 8; jj++) acc[i][jj] = 0.0f;

        for (int kt = 0; kt < 8; ++kt) {
            #pragma unroll
            for (int t = 0; t < 4; t++) {
                int f  = tid + 256 * t;
                int r  = f >> 3;
                int kq = f & 7;
                float4 av = *(const float4*)(z   + (size_t)(row0 + r) * E_DIM + kt * 32 + kq * 4);
                float4 bv = *(const float4*)(emb + (size_t)(jt * 128 + r) * E_DIM + kt * 32 + kq * 4);
                As[kq * 4 + 0][r] = av.x; As[kq * 4 + 1][r] = av.y;
                As[kq * 4 + 2][r] = av.z; As[kq * 4 + 3][r] = av.w;
                Bs[kq * 4 + 0][r] = bv.x; Bs[kq * 4 + 1][r] = bv.y;
                Bs[kq * 4 + 2][r] = bv.z; Bs[kq * 4 + 3][r] = bv.w;
            }
            __syncthreads();
            #pragma unroll
            for (int k = 0; k < 32; k++) {
                float4 a0 = *(const float4*)&As[k][trow * 4];
                float4 a1 = *(const float4*)&As[k][trow * 4 + 64];
                float4 b0 = *(const float4*)&Bs[k][tcol * 4];
                float4 b1 = *(const float4*)&Bs[k][tcol * 4 + 64];
                float a[8] = {a0.x, a0.y, a0.z, a0.w, a1.x, a1.y, a1.z, a1.w};
                float b[8] = {b0.x, b0.y, b0.z, b0.w, b1.x, b1.y, b1.z, b1.w};
                #pragma unroll
                for (int i = 0; i < 8; i++)
                    #pragma unroll
                    for (int jj = 0; jj < 8; jj++)
                        acc[i][jj] = fmaf(a[i], b[jj], acc[i][jj]);
            }
            __syncthreads();
        }

        float en8[8];
        #pragma unroll
        for (int jj = 0; jj < 8; jj++)
            en8[jj] = enf[jt * 128 + tcol * 4 + (jj & 3) + (jj >> 2) * 64];

        #pragma unroll
        for (int i = 0; i < 8; i++) {
            #pragma unroll
            for (int jj = 0; jj < 8; jj++) {
                int jg = jt * 128 + tcol * 4 + (jj & 3) + (jj >> 2) * 64;
                float A = czr[i] + en8[jj];          // fl32(Cz + Ce)  [ref assoc order]
                float q = A - 2.0f * acc[i][jj];     // fl32(A - 2M): 2*acc exact double
                unsigned long long kk =
                    ((unsigned long long)f2sort(-q) << 32) | (unsigned int)(4095 - jg);
                if (kk > key[i]) key[i] = kk;        // max(-q) == min(q), tie -> low j
            }
        }
    }

    // 16-lane butterfly per row
    #pragma unroll
    for (int i = 0; i < 8; i++) {
        unsigned long long k = key[i];
        #pragma unroll
        for (int off = 1; off < 16; off <<= 1) {
            unsigned long long ok = __shfl_xor(k, off);
            k = (ok > k) ? ok : k;
        }
        if (tcol == 0) {
            int grow = row0 + trow * 4 + (i & 3) + (i >> 2) * 64;
            idx[grow] = 4095 - (int)(k & 0xFFFFFFFFull);
        }
    }
}

// ---------- kernel 3: epilogue ----------
// d_out FLOAT32: [loss(1) | one-hot(32768*4096) | z_q_st(32768*256) |
//                 emb(4096*256) | indices(32768)]
__global__ __launch_bounds__(256) void k_epilogue(const float* __restrict__ z,
                                                  const float* __restrict__ emb,
                                                  const int* __restrict__ idx,
                                                  float* __restrict__ out,
                                                  double* __restrict__ rowloss) {
    const int row  = blockIdx.x * 4 + (threadIdx.x >> 6);
    const int lane = threadIdx.x & 63;
    const int j    = idx[row];
    float4 zv = *(const float4*)(z   + (size_t)row * E_DIM + lane * 4);
    float4 ev = *(const float4*)(emb + (size_t)j   * E_DIM + lane * 4);

    // z_q_st = fl32(z + fl32(z_q - z))  [ref assoc order]
    float4 st;
    st.x = zv.x + (ev.x - zv.x);
    st.y = zv.y + (ev.y - zv.y);
    st.z = zv.z + (ev.z - zv.z);
    st.w = zv.w + (ev.w - zv.w);
    const size_t zq0 = 1ull + (size_t)N_ROWS * N_E;
    *(float4*)(out + zq0 + (size_t)row * E_DIM + lane * 4) = st;

    double dx = (double)ev.x - zv.x, dy = (double)ev.y - zv.y;
    double dz = (double)ev.z - zv.z, dw = (double)ev.w - zv.w;
    double s = dx * dx + dy * dy + dz * dz + dw * dw;
    #pragma unroll
    for (int off = 1; off < 64; off <<= 1) s += __shfl_xor(s, off);

    if (lane == 0) {
        rowloss[row] = s;
        out[1ull + (size_t)row * N_E + j] = 1.0f;
        const size_t ix0 = 1ull + (size_t)N_ROWS * N_E + (size_t)N_ROWS * E_DIM
                         + (size_t)N_E * E_DIM;
        out[ix0 + row] = (float)j;
    }
}

// ---------- kernel 4: deterministic loss reduce ----------
__global__ __launch_bounds__(256) void k_loss(const double* __restrict__ rowloss,
                                              float* __restrict__ out) {
    __shared__ double sm[256];
    double s = 0.0;
    for (int i = threadIdx.x; i < N_ROWS; i += 256) s += rowloss[i];
    sm[threadIdx.x] = s;
    __syncthreads();
    for (int h = 128; h > 0; h >>= 1) {
        if (threadIdx.x < h) sm[threadIdx.x] += sm[threadIdx.x + h];
        __syncthreads();
    }
    if (threadIdx.x == 0)
        out[0] = (float)(sm[0] / ((double)N_ROWS * (double)E_DIM));
}

extern "C" void kernel_launch(void* const* d_in, const int* in_sizes, int n_in,
                              void* d_out, int out_size, void* d_ws, size_t ws_size,
                              hipStream_t stream) {
    const float* z   = (const float*)d_in[0];
    const float* emb = (const float*)d_in[1];
    float* out = (float*)d_out;

    char* ws = (char*)d_ws;
    float*  enf     = (float*)ws;                          // 16 KB
    float*  znf     = (float*)(ws + 16384);                // 128 KB
    int*    idx     = (int*)(ws + 16384 + 131072);         // 128 KB
    double* rowloss = (double*)(ws + 16384 + 262144);      // 256 KB

    // zero the one-hot region (f32 elements [1, 1+N*N_E))
    hipMemsetAsync(out + 1, 0, (size_t)N_ROWS * (size_t)N_E * sizeof(float), stream);

    // emb passthrough chunk: exact d2d copy
    const size_t emb0 = 1ull + (size_t)N_ROWS * N_E + (size_t)N_ROWS * E_DIM;
    hipMemcpyAsync(out + emb0, emb, (size_t)N_E * E_DIM * sizeof(float),
                   hipMemcpyDeviceToDevice, stream);

    k_rownorm <<<N_E / 4, 256, 0, stream>>>(emb, enf);
    k_rownorm <<<N_ROWS / 4, 256, 0, stream>>>(z, znf);
    k_passA   <<<N_ROWS / 128, 256, 0, stream>>>(z, emb, enf, znf, idx);
    k_epilogue<<<N_ROWS / 4, 256, 0, stream>>>(z, emb, idx, out, rowloss);
    k_loss    <<<1, 256, 0, stream>>>(rowloss, out);
}